// Round 2
// baseline (109.399 us; speedup 1.0000x reference)
//
#include <hip/hip_runtime.h>
#include <math.h>

#define N_OCT 16
#define NPAIR 8
#define NS    32768
#define TPB   512
#define SPT   (NS / TPB)   // 64 samples per thread
#define N_BE  512          // B*E = 8*64

typedef float v2f __attribute__((ext_vector_type(2)));

static __device__ __forceinline__ v2f fma2(v2f a, v2f b, v2f c) {
    return __builtin_elementwise_fma(a, b, c);
}

// Single fused kernel. vs R1-baseline (two-dispatch, 64 KiB fp16 LDS stage):
//  - per-octave constants computed by lanes t<16 in the block prologue
//    (identical math to the old setup kernel, incl. the sequential float
//    cumsum and the double-precision cos for the double-float c2 pair);
//    one dispatch instead of two, no d_ws dependency at all.
//  - normalization via two-pass RECOMPUTE of the linear recurrence instead
//    of staging samples in LDS: pass 1 tracks max only; norm is then folded
//    into the restored initial state (linearity), pass 2 stores normalized
//    fp32 straight to global (coalesced 4B/lane = 256B/instr).
//    Removes 64 ds_write_b16 + 16 ds_read_b64 per thread, the 64 KiB LDS
//    footprint, and the fp16 quantization that held absmax at the 0.015625
//    threshold edge.
// Cost: recurrence runs twice (~2x 1550 packed VALU ops/thread ~ 12.4 us
// issue at 4 waves/SIMD) but overlaps the 10.7 us HBM store floor.
// VGPR: 6 arrays x 8 v2f = 96 + temps, inside the 65..128 occupancy band
// (4 waves/SIMD, 2 blocks/CU — unchanged from baseline, which was LDS-capped
// at the same residency).
__global__ __launch_bounds__(TPB, 1)
void f0res_kernel(const float* __restrict__ f0_in,
                  const float* __restrict__ dc_in,
                  const float* __restrict__ fs_in,
                  float* __restrict__ out)
{
    __shared__ double sR[N_OCT];
    __shared__ float  sCH[N_OCT], sCL[N_OCT], sAMP[N_OCT];
    __shared__ float  wmax[TPB / 64];

    const int be = blockIdx.x;
    const int t  = threadIdx.x;

    // ---- per-block prologue: 16 lanes compute per-octave constants ----
    if (t < N_OCT) {
        const int o = t;
        const float f0a = fabsf(f0_in[be]);
        const float dc  = dc_in[be];
        const float fs  = fs_in[be];

        const float MINF = (float)(20.0 / 11025.0);
        const float FRNG = (float)(3000.0 / 11025.0 - 20.0 / 11025.0);

        // double sigmoid (reference applies sigmoid twice), decay ladder
        const float s1    = 1.0f / (1.0f + __expf(-dc));
        const float dv    = 1.0f / (1.0f + __expf(-s1));
        const float decay = 0.01f + dv * 0.9801f;          // (1-0.01)*0.99
        const float logd  = __logf(decay + 1e-12f);
        const float f0r   = (MINF + f0a * FRNG) * 3.14159274101257324f;

        // sequential float cumsum, bit-matching the reference's jnp.cumsum
        float cl = 0.f, cf = 0.f;
        for (int i = 0; i <= o; ++i) { cl += logd; cf += fs; }
        float ed  = __expf(cl);                            // decay^(o+1)
        float f0s = f0r * cf;                              // rad/sample
        float a   = ed;
        if (!(f0s < 1.0f)) { a = 0.0f; f0s = 0.0f; }       // nyquist cutoff

        const double inv2pi = 0.15915494309189535;
        double r = (double)f0s * inv2pi;                   // revolutions/sample

        // c2 = 2*cos(TPB*f0s) as a double-float pair: 2^-48 effective
        // frequency error (single-float c2 is ill-conditioned when
        // TPB*f0s mod 2pi ~ 0/pi)
        double drev = r * (double)TPB;
        drev -= floor(drev);
        double c2d = 2.0 * cos(drev * 6.283185307179586);
        float  ch  = (float)c2d;

        sR[o]   = r;
        sCH[o]  = ch;
        sCL[o]  = (float)(c2d - (double)ch);
        sAMP[o] = a;
    }
    __syncthreads();

    // ---- seed per-thread oscillator state (thread t owns s = k*TPB + t) ----
    // Paired per-octave state: component x = octave 2j, y = octave 2j+1
    v2f xp[NPAIR], xc[NPAIR], c2h[NPAIR], c2l[NPAIR], sx[NPAIR], sp[NPAIR];

    #pragma unroll
    for (int o = 0; o < N_OCT; ++o) {
        const double r = sR[o];
        const float  a = sAMP[o];

        double p0 = r * (double)(t + 1);               // phase at sample s=t
        p0 -= floor(p0);
        double pm = r * (double)(t + 1 - TPB);         // phase at s = t-TPB
        pm -= floor(pm);
        float xcur  = a * __builtin_amdgcn_sinf((float)p0);  // amp folded in
        float xprev = a * __builtin_amdgcn_sinf((float)pm);

        const int j = o >> 1;
        if ((o & 1) == 0) {
            xc[j].x = xcur;   xp[j].x = xprev;
            c2h[j].x = sCH[o]; c2l[j].x = sCL[o];
        } else {
            xc[j].y = xcur;   xp[j].y = xprev;
            c2h[j].y = sCH[o]; c2l[j].y = sCL[o];
        }
    }
    // save seeds for pass 2 (re-seeding would redo 32 fp64+sin chains)
    #pragma unroll
    for (int j = 0; j < NPAIR; ++j) { sx[j] = xc[j]; sp[j] = xp[j]; }

    // ---- pass 1: Chebyshev recurrence, block-max only ----
    float lmax = 0.0f;
    #pragma unroll 4
    for (int k = 0; k < SPT; ++k) {
        v2f acc2 = (v2f)(0.0f);
        #pragma unroll
        for (int j = 0; j < NPAIR; ++j) {
            acc2 += xc[j];                              // amp pre-folded
            v2f xn = fma2(c2h[j], xc[j], fma2(c2l[j], xc[j], -xp[j]));
            xp[j] = xc[j];
            xc[j] = xn;
        }
        lmax = fmaxf(lmax, fabsf(acc2.x + acc2.y));
    }

    // ---- block max reduction: wave shuffle then tiny LDS ----
    #pragma unroll
    for (int off = 32; off > 0; off >>= 1)
        lmax = fmaxf(lmax, __shfl_down(lmax, off, 64));
    if ((t & 63) == 0) wmax[t >> 6] = lmax;
    __syncthreads();
    float bmax = wmax[0];
    #pragma unroll
    for (int w = 1; w < TPB / 64; ++w) bmax = fmaxf(bmax, wmax[w]);

    const float norm = 1.0f / (bmax + 1e-8f);

    // ---- pass 2: restore state pre-scaled by norm (linear recurrence ->
    // normalization folds into the seed), store normalized fp32 direct ----
    #pragma unroll
    for (int j = 0; j < NPAIR; ++j) {
        xc[j] = sx[j] * norm;
        xp[j] = sp[j] * norm;
    }

    float* __restrict__ orow = out + (size_t)be * NS;
    #pragma unroll 4
    for (int k = 0; k < SPT; ++k) {
        v2f acc2 = (v2f)(0.0f);
        #pragma unroll
        for (int j = 0; j < NPAIR; ++j) {
            acc2 += xc[j];
            v2f xn = fma2(c2h[j], xc[j], fma2(c2l[j], xc[j], -xp[j]));
            xp[j] = xc[j];
            xc[j] = xn;
        }
        orow[k * TPB + t] = acc2.x + acc2.y;           // coalesced dword store
    }
}

extern "C" void kernel_launch(void* const* d_in, const int* in_sizes, int n_in,
                              void* d_out, int out_size, void* d_ws, size_t ws_size,
                              hipStream_t stream) {
    const float* f0 = (const float*)d_in[0];
    const float* dc = (const float*)d_in[1];
    const float* fs = (const float*)d_in[3];   // d_in[2] is "unused"
    float* out = (float*)d_out;
    (void)d_ws; (void)ws_size;

    hipLaunchKernelGGL(f0res_kernel, dim3(N_BE), dim3(TPB),
                       0, stream, f0, dc, fs, out);
}

// Round 3
// 108.710 us; speedup vs baseline: 1.0063x; 1.0063x over previous
//
#include <hip/hip_runtime.h>
#include <math.h>

#define N_OCT 16
#define NS    32768
#define TPB   1024
#define SPT   (NS / TPB)   // 32 samples per thread
#define N_BE  512          // B*E = 8*64

typedef float v2f __attribute__((ext_vector_type(2)));

static __device__ __forceinline__ v2f fma2(v2f a, v2f b, v2f c) {
    return __builtin_elementwise_fma(a, b, c);
}

// R3 structure (vs R2's two-pass full-16-octave kernel, 46.2us, VALUBusy 63%,
// Occ 26%):
//  1. DEAD-OCTAVE SKIP (exact): f0s_o = f0r * cumsum(fs) is non-decreasing in
//     o, so the nyquist cut (f0s<1 else amp=0) zeroes a SUFFIX of octaves.
//     Zero-amp oscillator state is identically 0 -> skipping it is bit-exact.
//     Live count L via __ballot in the prologue; block-uniform dispatch to a
//     template<NP> body (static array indexing only -- runtime-indexed
//     ext_vector arrays go to scratch). Expected live ~7/16 -> ~2x less work.
//  2. BACKWARD PASS 2: Chebyshev recurrence is reversible
//     (y_{k-1} = c2*y_k - y_{k+1}), so the store pass runs backward from pass
//     1's end state. Kills the sx/sp seed-save arrays (-32 VGPRs) that forced
//     the compiler to 64 VGPRs with in-loop LDS rematerialization (R2: 29us
//     of VALU issue vs ~12us ideal, 37% stall).
//  3. TPB 512->1024: 8192 waves total = all wave slots fillable (R2 grid only
//     reached ~2 waves/SIMD effective; latency-hiding starved).
// Normalization still folds into the state (linear recurrence): both backward
// seeds are pre-scaled by norm.
template<int NP>
static __device__ __forceinline__ void run_body(
    const int t,
    const double* __restrict__ sR, const float* __restrict__ sCH,
    const float* __restrict__ sCL, const float* __restrict__ sAMP,
    float* __restrict__ wmax, float* __restrict__ orow)
{
    v2f xp[NP], xc[NP], c2h[NP], c2l[NP];

    // seed: y0 = amp*sin((t+1)*theta), y(-1) = amp*sin((t+1-TPB)*theta)
    #pragma unroll
    for (int o = 0; o < 2 * NP; ++o) {
        const double r = sR[o];                        // revolutions/sample
        const float  a = sAMP[o];                      // 0 for dead octaves
        double p0 = r * (double)(t + 1);
        p0 -= floor(p0);
        double pm = r * (double)(t + 1 - TPB);
        pm -= floor(pm);
        float xcur  = a * __builtin_amdgcn_sinf((float)p0);   // amp folded in
        float xprev = a * __builtin_amdgcn_sinf((float)pm);
        const int j = o >> 1;
        if ((o & 1) == 0) {
            xc[j].x = xcur;   xp[j].x = xprev;
            c2h[j].x = sCH[o]; c2l[j].x = sCL[o];
        } else {
            xc[j].y = xcur;   xp[j].y = xprev;
            c2h[j].y = sCH[o]; c2l[j].y = sCL[o];
        }
    }

    // ---- pass 1 (forward): block-max only, no stores ----
    float lmax = 0.0f;
    #pragma unroll 4
    for (int k = 0; k < SPT; ++k) {
        v2f acc2 = (v2f)(0.0f);
        #pragma unroll
        for (int j = 0; j < NP; ++j) {
            acc2 += xc[j];
            v2f xn = fma2(c2h[j], xc[j], fma2(c2l[j], xc[j], -xp[j]));
            xp[j] = xc[j];
            xc[j] = xn;
        }
        lmax = fmaxf(lmax, fabsf(acc2.x + acc2.y));
    }
    // after k=SPT-1: xc = y[SPT], xp = y[SPT-1]

    // ---- block max: wave shuffle then tiny LDS ----
    #pragma unroll
    for (int off = 32; off > 0; off >>= 1)
        lmax = fmaxf(lmax, __shfl_down(lmax, off, 64));
    if ((t & 63) == 0) wmax[t >> 6] = lmax;
    __syncthreads();
    float bmax = wmax[0];
    #pragma unroll
    for (int w = 1; w < TPB / 64; ++w) bmax = fmaxf(bmax, wmax[w]);
    const float norm = 1.0f / (bmax + 1e-8f);

    // ---- pass 2 (backward): y_{m-1} = c2*y_m - y_{m+1}, norm folded ----
    v2f cur[NP], nxt[NP];
    #pragma unroll
    for (int j = 0; j < NP; ++j) {
        cur[j] = xp[j] * norm;                         // y[SPT-1] scaled
        nxt[j] = xc[j] * norm;                         // y[SPT]   scaled
    }
    #pragma unroll 4
    for (int m = SPT - 1; m >= 0; --m) {
        v2f acc2 = (v2f)(0.0f);
        #pragma unroll
        for (int j = 0; j < NP; ++j) {
            acc2 += cur[j];                            // sample y[m]
            v2f pv = fma2(c2h[j], cur[j], fma2(c2l[j], cur[j], -nxt[j]));
            nxt[j] = cur[j];
            cur[j] = pv;
        }
        orow[m * TPB + t] = acc2.x + acc2.y;           // coalesced dword store
    }
}

__global__ __launch_bounds__(TPB, 1)
void f0res_kernel(const float* __restrict__ f0_in,
                  const float* __restrict__ dc_in,
                  const float* __restrict__ fs_in,
                  float* __restrict__ out)
{
    __shared__ double sR[N_OCT];
    __shared__ float  sCH[N_OCT], sCL[N_OCT], sAMP[N_OCT];
    __shared__ float  wmax[TPB / 64];
    __shared__ int    sLive;

    const int be = blockIdx.x;
    const int t  = threadIdx.x;

    // ---- prologue: lanes t<16 compute per-octave constants ----
    if (t < N_OCT) {
        const int o = t;
        const float f0a = fabsf(f0_in[be]);
        const float dc  = dc_in[be];
        const float fs  = fs_in[be];

        const float MINF = (float)(20.0 / 11025.0);
        const float FRNG = (float)(3000.0 / 11025.0 - 20.0 / 11025.0);

        // double sigmoid (reference applies sigmoid twice), decay ladder
        const float s1    = 1.0f / (1.0f + __expf(-dc));
        const float dv    = 1.0f / (1.0f + __expf(-s1));
        const float decay = 0.01f + dv * 0.9801f;          // (1-0.01)*0.99
        const float logd  = __logf(decay + 1e-12f);
        const float f0r   = (MINF + f0a * FRNG) * 3.14159274101257324f;

        // sequential float cumsum, bit-matching the reference's jnp.cumsum
        float cl = 0.f, cf = 0.f;
        for (int i = 0; i <= o; ++i) { cl += logd; cf += fs; }
        float ed  = __expf(cl);                            // decay^(o+1)
        float f0s = f0r * cf;                              // rad/sample
        float a   = ed;
        const bool live = (f0s < 1.0f);                    // nyquist cutoff
        if (!live) { a = 0.0f; f0s = 0.0f; }

        // live octaves form a prefix (f0s non-decreasing in o)
        unsigned long long lm = __ballot(live);
        if (o == 0) sLive = __popcll(lm);

        const double inv2pi = 0.15915494309189535;
        double r = (double)f0s * inv2pi;                   // revolutions/sample

        // c2 = 2*cos(TPB*f0s) as a double-float pair: 2^-48 effective
        // frequency error (single-float c2 is ill-conditioned when
        // TPB*f0s mod 2pi ~ 0/pi)
        double drev = r * (double)TPB;
        drev -= floor(drev);
        double c2d = 2.0 * cos(drev * 6.283185307179586);
        float  ch  = (float)c2d;

        sR[o]   = r;
        sCH[o]  = ch;
        sCL[o]  = (float)(c2d - (double)ch);
        sAMP[o] = a;
    }
    __syncthreads();

    const int NP = (sLive + 1) >> 1;                   // live octave PAIRS
    float* __restrict__ orow = out + (size_t)be * NS;

    // block-uniform dispatch; each case is fully statically indexed
    switch (NP) {
    case 0: {
        #pragma unroll
        for (int m = 0; m < SPT; ++m) orow[m * TPB + t] = 0.0f;
        break;
    }
    case 1: run_body<1>(t, sR, sCH, sCL, sAMP, wmax, orow); break;
    case 2: run_body<2>(t, sR, sCH, sCL, sAMP, wmax, orow); break;
    case 3: run_body<3>(t, sR, sCH, sCL, sAMP, wmax, orow); break;
    case 4: run_body<4>(t, sR, sCH, sCL, sAMP, wmax, orow); break;
    case 5: run_body<5>(t, sR, sCH, sCL, sAMP, wmax, orow); break;
    case 6: run_body<6>(t, sR, sCH, sCL, sAMP, wmax, orow); break;
    case 7: run_body<7>(t, sR, sCH, sCL, sAMP, wmax, orow); break;
    default: run_body<8>(t, sR, sCH, sCL, sAMP, wmax, orow); break;
    }
}

extern "C" void kernel_launch(void* const* d_in, const int* in_sizes, int n_in,
                              void* d_out, int out_size, void* d_ws, size_t ws_size,
                              hipStream_t stream) {
    const float* f0 = (const float*)d_in[0];
    const float* dc = (const float*)d_in[1];
    const float* fs = (const float*)d_in[3];   // d_in[2] is "unused"
    float* out = (float*)d_out;
    (void)d_ws; (void)ws_size;

    hipLaunchKernelGGL(f0res_kernel, dim3(N_BE), dim3(TPB),
                       0, stream, f0, dc, fs, out);
}